// Round 2
// baseline (1938.327 us; speedup 1.0000x reference)
//
#include <hip/hip_runtime.h>
#include <hip/hip_bf16.h>
#include <type_traits>

#define BDIM 512
#define NB   128
#define SS   48
#define DD   8
#define HDIM 8
#define NL   8
#define NC   7
// LDS layout [i][d][j]: offset = i*RS + d*SS + j.  RS odd => both access
// orientations (lane-stride RS and lane-stride 1) are conflict-free.
#define RS   385
#define HSZ  (SS*RS)            // 18480 floats per buffer
#define SMEM_FLOATS (2*HSZ + 528 + 784 + 8)
#define SMEM_BYTES  (SMEM_FLOATS*4)

__device__ __forceinline__ float l2f(const float v)           { return v; }
__device__ __forceinline__ float l2f(const __hip_bfloat16 v)  { return __bfloat162float(v); }
__device__ __forceinline__ void  stf(float* p, float v)          { *p = v; }
__device__ __forceinline__ void  stf(__hip_bfloat16* p, float v) { *p = __float2bfloat16(v); }
__device__ __forceinline__ float rl(float v, int l) {
    return __int_as_float(__builtin_amdgcn_readlane(__float_as_int(v), l));
}

// One axial-attention phase over LDS-resident state (dtype-free).
// colphase=0: problems are columns, tokens are rows -> write o_row into ab.
// colphase=1: problems are rows, tokens are cols -> h = relu(o_col + ab).
// wb layout: [0,64) Wq, [64,128) Wk, [128,192) Wv, [192,256) Wo, [256,264) bo.
__device__ __attribute__((noinline))
void attn_phase(float* __restrict__ hb, float* __restrict__ ab,
                const float* __restrict__ wb, int wav, int lane, int tl, int colphase)
{
    #pragma unroll 1
    for (int p = 0; p < 6; ++p) {
        const int prob = wav + p*8;
        const int base = colphase ? (prob*RS + tl) : (tl*RS + prob);

        float ht[DD];
        #pragma unroll
        for (int d = 0; d < DD; ++d) ht[d] = hb[base + d*SS];

        // q/k/v projections; fold 0.5 (E^-0.5) * log2(e) into q for exp2.
        float q[HDIM], k[HDIM], v[HDIM];
        #pragma unroll
        for (int o = 0; o < HDIM; ++o) {
            float aq = 0.f, ak = 0.f, av = 0.f;
            #pragma unroll
            for (int d = 0; d < DD; ++d) {
                aq += ht[d] * wb[o*8 + d];
                ak += ht[d] * wb[64 + o*8 + d];
                av += ht[d] * wb[128 + o*8 + d];
            }
            q[o] = aq * 0.72134752044f;  // 0.5 * log2(e)
            k[o] = ak; v[o] = av;
        }

        float ov[HDIM];
        #pragma unroll
        for (int hh = 0; hh < 2; ++hh) {
            float dt[SS];
            #pragma unroll
            for (int j2 = 0; j2 < SS; ++j2) {
                float acc =  q[hh*4+0] * rl(k[hh*4+0], j2);
                acc       += q[hh*4+1] * rl(k[hh*4+1], j2);
                acc       += q[hh*4+2] * rl(k[hh*4+2], j2);
                acc       += q[hh*4+3] * rl(k[hh*4+3], j2);
                dt[j2] = acc;
            }
            float m = dt[0];
            #pragma unroll
            for (int j2 = 1; j2 < SS; ++j2) m = fmaxf(m, dt[j2]);
            float s = 0.f;
            #pragma unroll
            for (int j2 = 0; j2 < SS; ++j2) {
                float pv = exp2f(dt[j2] - m);
                dt[j2] = pv; s += pv;
            }
            float o0 = 0.f, o1 = 0.f, o2 = 0.f, o3 = 0.f;
            #pragma unroll
            for (int j2 = 0; j2 < SS; ++j2) {
                float pv = dt[j2];
                o0 += pv * rl(v[hh*4+0], j2);
                o1 += pv * rl(v[hh*4+1], j2);
                o2 += pv * rl(v[hh*4+2], j2);
                o3 += pv * rl(v[hh*4+3], j2);
            }
            float rs = 1.f / s;
            ov[hh*4+0] = o0*rs; ov[hh*4+1] = o1*rs;
            ov[hh*4+2] = o2*rs; ov[hh*4+3] = o3*rs;
        }

        if (lane < SS) {
            #pragma unroll
            for (int d = 0; d < DD; ++d) {
                float acc = wb[256 + d];
                #pragma unroll
                for (int o2 = 0; o2 < HDIM; ++o2) acc += ov[o2] * wb[192 + d*8 + o2];
                const int idx = base + d*SS;
                if (colphase) hb[idx] = fmaxf(0.f, acc + ab[idx]);
                else          ab[idx] = acc;
            }
        }
    }
}

template <typename T>
__global__ void __launch_bounds__(BDIM, 2)
axial_kernel(const void* xv, const void* enc_wv, const void* enc_bv,
             const void* pos_rowv, const void* pos_colv,
             const void* Wqv, const void* Wkv, const void* Wvv, const void* Wov,
             const void* bov, const void* cls_wv, const void* cls_bv, void* outv)
{
    // ---- dtype sniff on x: low 16 bits of each dword are a plausible bf16
    // (exp in [100,150]) iff the data is bf16-packed; for fp32 they're random
    // mantissa bits (in-range prob ~0.19). 32 samples separate by >6 sigma.
    const unsigned* xu = (const unsigned*)xv;
    int cnt = 0;
    #pragma unroll
    for (int t = 0; t < 32; ++t) {
        const unsigned w = xu[t];
        const int e = (w >> 7) & 0xff;
        cnt += (e > 100 && e < 150) ? 1 : 0;
    }
    const bool isbf = (cnt >= 20);
    constexpr bool wantbf = std::is_same<T, __hip_bfloat16>::value;
    if (isbf != wantbf) return;   // wrong-dtype instantiation: no-op

    const T* x       = (const T*)xv;
    const T* enc_w   = (const T*)enc_wv;
    const T* enc_b   = (const T*)enc_bv;
    const T* pos_row = (const T*)pos_rowv;
    const T* pos_col = (const T*)pos_colv;
    const T* Wq      = (const T*)Wqv;
    const T* Wk      = (const T*)Wkv;
    const T* Wv      = (const T*)Wvv;
    const T* Wo      = (const T*)Wov;
    const T* bo      = (const T*)bov;
    const T* cls_w   = (const T*)cls_wv;
    const T* cls_b   = (const T*)cls_bv;
    T*       out     = (T*)outv;

    extern __shared__ float smem[];
    float* hb = smem;              // h image           [HSZ]
    float* ab = hb + HSZ;          // o_row accumulator [HSZ]
    float* wb = ab + HSZ;          // layer weights (2 axes) [528]
    float* eb = wb + 528;          // enc_w/enc_b/pos_row/pos_col [784]
    float* cb = eb + 784;          // classifier logits [8]

    const int b    = blockIdx.x;
    const int tid  = threadIdx.x;
    const int lane = tid & 63;
    const int wav  = tid >> 6;
    const int tl   = lane < SS ? lane : SS-1;

    // stage encoder/pos params
    for (int f = tid; f < 784; f += BDIM) {
        float v;
        if (f < 8)        v = l2f(enc_w[f]);
        else if (f < 16)  v = l2f(enc_b[f-8]);
        else if (f < 400) v = l2f(pos_row[f-16]);
        else              v = l2f(pos_col[f-400]);
        eb[f] = v;
    }
    __syncthreads();

    // encoder: h = relu(x*enc_w + enc_b) + pos_row[i] + pos_col[j]
    const T* xb = x + (size_t)b * SS * SS;
    for (int p = tid; p < SS*SS; p += BDIM) {
        const int i = p / SS, j = p % SS;
        const float xv2 = l2f(xb[p]);
        #pragma unroll
        for (int d = 0; d < DD; ++d) {
            float hv = fmaxf(0.f, xv2*eb[d] + eb[8+d]) + eb[16 + i*8 + d] + eb[400 + j*8 + d];
            hb[i*RS + d*SS + j] = hv;
        }
    }

    #pragma unroll 1
    for (int l = 0; l < NL; ++l) {
        __syncthreads();
        for (int f = tid; f < 528; f += BDIM) {
            const int a  = f < 264 ? 0 : 1;
            const int r  = f - a*264;
            const int la = l*2 + a;
            float v;
            if (r < 64)       v = l2f(Wq[la*64 + r]);
            else if (r < 128) v = l2f(Wk[la*64 + r-64]);
            else if (r < 192) v = l2f(Wv[la*64 + r-128]);
            else if (r < 256) v = l2f(Wo[la*64 + r-192]);
            else              v = l2f(bo[la*8 + r-256]);
            wb[f] = v;
        }
        __syncthreads();
        attn_phase(hb, ab, wb,       wav, lane, tl, 0);   // row attention -> ab
        __syncthreads();
        attn_phase(hb, ab, wb + 264, wav, lane, tl, 1);   // col attention, fuse into hb
    }
    __syncthreads();

    // max over d -> ab[p] (flat reuse)
    for (int p = tid; p < SS*SS; p += BDIM) {
        const int i = p / SS, j = p % SS;
        float mv = hb[i*RS + j];
        #pragma unroll
        for (int d = 1; d < DD; ++d) mv = fmaxf(mv, hb[i*RS + d*SS + j]);
        ab[p] = mv;
    }
    if (tid < NC) cb[tid] = l2f(cls_b[tid]);
    __syncthreads();

    float part[NC] = {0.f,0.f,0.f,0.f,0.f,0.f,0.f};
    for (int p = tid; p < SS*SS; p += BDIM) {
        const float mv = ab[p];
        #pragma unroll
        for (int c = 0; c < NC; ++c) part[c] += mv * l2f(cls_w[c*(SS*SS) + p]);
    }
    #pragma unroll
    for (int c = 0; c < NC; ++c) {
        #pragma unroll
        for (int off = 32; off > 0; off >>= 1) part[c] += __shfl_down(part[c], off, 64);
    }
    if (lane == 0) {
        #pragma unroll
        for (int c = 0; c < NC; ++c) atomicAdd(&cb[c], part[c]);
    }
    __syncthreads();

    if (tid < NC) {
        float m = cb[0];
        #pragma unroll
        for (int c = 1; c < NC; ++c) m = fmaxf(m, cb[c]);
        float s = 0.f;
        #pragma unroll
        for (int c = 0; c < NC; ++c) s += exp2f((cb[c]-m) * 1.44269504089f);
        const float e = exp2f((cb[tid]-m) * 1.44269504089f);
        stf(&out[b*NC + tid], e / s);
    }
}

extern "C" void kernel_launch(void* const* d_in, const int* in_sizes, int n_in,
                              void* d_out, int out_size, void* d_ws, size_t ws_size,
                              hipStream_t stream) {
    (void)in_sizes; (void)n_in; (void)d_ws; (void)ws_size; (void)out_size;
    hipFuncSetAttribute(reinterpret_cast<const void*>(&axial_kernel<float>),
                        hipFuncAttributeMaxDynamicSharedMemorySize, SMEM_BYTES);
    hipFuncSetAttribute(reinterpret_cast<const void*>(&axial_kernel<__hip_bfloat16>),
                        hipFuncAttributeMaxDynamicSharedMemorySize, SMEM_BYTES);
    axial_kernel<float><<<NB, BDIM, SMEM_BYTES, stream>>>(
        d_in[0], d_in[1], d_in[2], d_in[3], d_in[4], d_in[5],
        d_in[6], d_in[7], d_in[8], d_in[9], d_in[10], d_in[11], d_out);
    axial_kernel<__hip_bfloat16><<<NB, BDIM, SMEM_BYTES, stream>>>(
        d_in[0], d_in[1], d_in[2], d_in[3], d_in[4], d_in[5],
        d_in[6], d_in[7], d_in[8], d_in[9], d_in[10], d_in[11], d_out);
}

// Round 3
// 1807.776 us; speedup vs baseline: 1.0722x; 1.0722x over previous
//
#include <hip/hip_runtime.h>
#include <hip/hip_bf16.h>
#include <type_traits>

#define BDIM 512
#define NB   128
#define SS   48
#define DD   8
#define HDIM 8
#define NL   8
#define NC   7
// LDS layout [i][d][j]: offset = i*RS + d*SS + j.  RS odd => both access
// orientations (lane-stride RS and lane-stride 1) are conflict-free.
#define RS   385
#define HSZ  (SS*RS)            // 18480 floats per buffer
#define SMEM_FLOATS (2*HSZ + 528 + 784 + 8)
#define SMEM_BYTES  (SMEM_FLOATS*4)

__device__ __forceinline__ float l2f(const float v)           { return v; }
__device__ __forceinline__ float l2f(const __hip_bfloat16 v)  { return __bfloat162float(v); }
__device__ __forceinline__ void  stf(float* p, float v)          { *p = v; }
__device__ __forceinline__ void  stf(__hip_bfloat16* p, float v) { *p = __float2bfloat16(v); }
__device__ __forceinline__ float rl(float v, int l) {
    return __int_as_float(__builtin_amdgcn_readlane(__float_as_int(v), l));
}

// One axial-attention phase over LDS-resident state.
// COLPHASE=0: problems are columns, tokens are rows -> write o_row into ab.
// COLPHASE=1: problems are rows, tokens are cols -> h = relu(o_col + ab).
// wb layout: [0,64) Wq, [64,128) Wk, [128,192) Wv, [192,256) Wo, [256,264) bo.
template <int COLPHASE>
__device__ __attribute__((noinline))
void attn_phase(float* __restrict__ hb, float* __restrict__ ab,
                const float* __restrict__ wb, int wav, int lane, int tl)
{
    #pragma unroll 1
    for (int p = 0; p < 6; ++p) {
        const int prob = wav + p*8;
        const int base = COLPHASE ? (prob*RS + tl) : (tl*RS + prob);

        float ht[DD];
        #pragma unroll
        for (int d = 0; d < DD; ++d) ht[d] = hb[base + d*SS];

        // q/k/v projections; fold 0.5 (E^-0.5) * log2(e) into q for exp2.
        float q[HDIM], k[HDIM], v[HDIM];
        #pragma unroll
        for (int o = 0; o < HDIM; ++o) {
            float aq = 0.f, ak = 0.f, av = 0.f;
            #pragma unroll
            for (int d = 0; d < DD; ++d) {
                aq += ht[d] * wb[o*8 + d];
                ak += ht[d] * wb[64 + o*8 + d];
                av += ht[d] * wb[128 + o*8 + d];
            }
            q[o] = aq * 0.72134752044f;  // 0.5 * log2(e)
            k[o] = ak; v[o] = av;
        }

        float ov[HDIM];
        #pragma unroll
        for (int hh = 0; hh < 2; ++hh) {
            float dt[SS];
            #pragma unroll
            for (int j2 = 0; j2 < SS; ++j2) {
                float acc =  q[hh*4+0] * rl(k[hh*4+0], j2);
                acc       += q[hh*4+1] * rl(k[hh*4+1], j2);
                acc       += q[hh*4+2] * rl(k[hh*4+2], j2);
                acc       += q[hh*4+3] * rl(k[hh*4+3], j2);
                dt[j2] = acc;
            }
            float m = dt[0];
            #pragma unroll
            for (int j2 = 1; j2 < SS; ++j2) m = fmaxf(m, dt[j2]);
            float s = 0.f;
            #pragma unroll
            for (int j2 = 0; j2 < SS; ++j2) {
                float pv = exp2f(dt[j2] - m);
                dt[j2] = pv; s += pv;
            }
            float o0 = 0.f, o1 = 0.f, o2 = 0.f, o3 = 0.f;
            #pragma unroll
            for (int j2 = 0; j2 < SS; ++j2) {
                float pv = dt[j2];
                o0 += pv * rl(v[hh*4+0], j2);
                o1 += pv * rl(v[hh*4+1], j2);
                o2 += pv * rl(v[hh*4+2], j2);
                o3 += pv * rl(v[hh*4+3], j2);
            }
            float rs = 1.f / s;
            ov[hh*4+0] = o0*rs; ov[hh*4+1] = o1*rs;
            ov[hh*4+2] = o2*rs; ov[hh*4+3] = o3*rs;
        }

        if (lane < SS) {
            #pragma unroll
            for (int d = 0; d < DD; ++d) {
                float acc = wb[256 + d];
                #pragma unroll
                for (int o2 = 0; o2 < HDIM; ++o2) acc += ov[o2] * wb[192 + d*8 + o2];
                const int idx = base + d*SS;
                if (COLPHASE) hb[idx] = fmaxf(0.f, acc + ab[idx]);
                else          ab[idx] = acc;
            }
        }
    }
}

template <typename T>
__global__ void __launch_bounds__(BDIM, 1)
axial_kernel(const void* xv, const void* enc_wv, const void* enc_bv,
             const void* pos_rowv, const void* pos_colv,
             const void* Wqv, const void* Wkv, const void* Wvv, const void* Wov,
             const void* bov, const void* cls_wv, const void* cls_bv, void* outv)
{
    // dtype sniff on x (robustness): low 16 bits of each dword are a plausible
    // bf16 exponent iff data is bf16-packed; random mantissa bits if fp32.
    const unsigned* xu = (const unsigned*)xv;
    int cnt = 0;
    #pragma unroll
    for (int t = 0; t < 32; ++t) {
        const unsigned w = xu[t];
        const int e = (w >> 7) & 0xff;
        cnt += (e > 100 && e < 150) ? 1 : 0;
    }
    const bool isbf = (cnt >= 20);
    constexpr bool wantbf = std::is_same<T, __hip_bfloat16>::value;
    if (isbf != wantbf) return;   // wrong-dtype instantiation: no-op

    const T* x       = (const T*)xv;
    const T* enc_w   = (const T*)enc_wv;
    const T* enc_b   = (const T*)enc_bv;
    const T* pos_row = (const T*)pos_rowv;
    const T* pos_col = (const T*)pos_colv;
    const T* Wq      = (const T*)Wqv;
    const T* Wk      = (const T*)Wkv;
    const T* Wv      = (const T*)Wvv;
    const T* Wo      = (const T*)Wov;
    const T* bo      = (const T*)bov;
    const T* cls_w   = (const T*)cls_wv;
    const T* cls_b   = (const T*)cls_bv;
    T*       out     = (T*)outv;

    extern __shared__ float smem[];
    float* hb = smem;              // h image           [HSZ]
    float* ab = hb + HSZ;          // o_row accumulator [HSZ]
    float* wb = ab + HSZ;          // layer weights (2 axes) [528]
    float* eb = wb + 528;          // enc_w/enc_b/pos_row/pos_col [784]
    float* cb = eb + 784;          // classifier logits [8]

    const int b    = blockIdx.x;
    const int tid  = threadIdx.x;
    const int lane = tid & 63;
    const int wav  = tid >> 6;
    const int tl   = lane < SS ? lane : SS-1;

    // stage encoder/pos params
    for (int f = tid; f < 784; f += BDIM) {
        float v;
        if (f < 8)        v = l2f(enc_w[f]);
        else if (f < 16)  v = l2f(enc_b[f-8]);
        else if (f < 400) v = l2f(pos_row[f-16]);
        else              v = l2f(pos_col[f-400]);
        eb[f] = v;
    }
    __syncthreads();

    // encoder: h = relu(x*enc_w + enc_b) + pos_row[i] + pos_col[j]
    const T* xb = x + (size_t)b * SS * SS;
    for (int p = tid; p < SS*SS; p += BDIM) {
        const int i = p / SS, j = p % SS;
        const float xv2 = l2f(xb[p]);
        #pragma unroll
        for (int d = 0; d < DD; ++d) {
            float hv = fmaxf(0.f, xv2*eb[d] + eb[8+d]) + eb[16 + i*8 + d] + eb[400 + j*8 + d];
            hb[i*RS + d*SS + j] = hv;
        }
    }

    #pragma unroll 1
    for (int l = 0; l < NL; ++l) {
        __syncthreads();
        for (int f = tid; f < 528; f += BDIM) {
            const int a  = f < 264 ? 0 : 1;
            const int r  = f - a*264;
            const int la = l*2 + a;
            float v;
            if (r < 64)       v = l2f(Wq[la*64 + r]);
            else if (r < 128) v = l2f(Wk[la*64 + r-64]);
            else if (r < 192) v = l2f(Wv[la*64 + r-128]);
            else if (r < 256) v = l2f(Wo[la*64 + r-192]);
            else              v = l2f(bo[la*8 + r-256]);
            wb[f] = v;
        }
        __syncthreads();
        attn_phase<0>(hb, ab, wb,       wav, lane, tl);   // row attention -> ab
        __syncthreads();
        attn_phase<1>(hb, ab, wb + 264, wav, lane, tl);   // col attention, fuse into hb
    }
    __syncthreads();

    // max over d -> ab[p] (flat reuse)
    for (int p = tid; p < SS*SS; p += BDIM) {
        const int i = p / SS, j = p % SS;
        float mv = hb[i*RS + j];
        #pragma unroll
        for (int d = 1; d < DD; ++d) mv = fmaxf(mv, hb[i*RS + d*SS + j]);
        ab[p] = mv;
    }
    if (tid < NC) cb[tid] = l2f(cls_b[tid]);
    __syncthreads();

    float part[NC] = {0.f,0.f,0.f,0.f,0.f,0.f,0.f};
    for (int p = tid; p < SS*SS; p += BDIM) {
        const float mv = ab[p];
        #pragma unroll
        for (int c = 0; c < NC; ++c) part[c] += mv * l2f(cls_w[c*(SS*SS) + p]);
    }
    #pragma unroll
    for (int c = 0; c < NC; ++c) {
        #pragma unroll
        for (int off = 32; off > 0; off >>= 1) part[c] += __shfl_down(part[c], off, 64);
    }
    if (lane == 0) {
        #pragma unroll
        for (int c = 0; c < NC; ++c) atomicAdd(&cb[c], part[c]);
    }
    __syncthreads();

    if (tid < NC) {
        float m = cb[0];
        #pragma unroll
        for (int c = 1; c < NC; ++c) m = fmaxf(m, cb[c]);
        float s = 0.f;
        #pragma unroll
        for (int c = 0; c < NC; ++c) s += exp2f((cb[c]-m) * 1.44269504089f);
        const float e = exp2f((cb[tid]-m) * 1.44269504089f);
        stf(&out[b*NC + tid], e / s);
    }
}

extern "C" void kernel_launch(void* const* d_in, const int* in_sizes, int n_in,
                              void* d_out, int out_size, void* d_ws, size_t ws_size,
                              hipStream_t stream) {
    (void)in_sizes; (void)n_in; (void)d_ws; (void)ws_size; (void)out_size;
    hipFuncSetAttribute(reinterpret_cast<const void*>(&axial_kernel<float>),
                        hipFuncAttributeMaxDynamicSharedMemorySize, SMEM_BYTES);
    hipFuncSetAttribute(reinterpret_cast<const void*>(&axial_kernel<__hip_bfloat16>),
                        hipFuncAttributeMaxDynamicSharedMemorySize, SMEM_BYTES);
    axial_kernel<float><<<NB, BDIM, SMEM_BYTES, stream>>>(
        d_in[0], d_in[1], d_in[2], d_in[3], d_in[4], d_in[5],
        d_in[6], d_in[7], d_in[8], d_in[9], d_in[10], d_in[11], d_out);
    axial_kernel<__hip_bfloat16><<<NB, BDIM, SMEM_BYTES, stream>>>(
        d_in[0], d_in[1], d_in[2], d_in[3], d_in[4], d_in[5],
        d_in[6], d_in[7], d_in[8], d_in[9], d_in[10], d_in[11], d_out);
}